// Round 6
// baseline (356.299 us; speedup 1.0000x reference)
//
#include <hip/hip_runtime.h>
#include <hip/hip_bf16.h>
#include <hip/hip_fp16.h>

#define B_ 32
#define T_ 2048
#define D_ 1024
#define U_ 1024
#define M_ (B_ * T_)   // 65536
#define NT_ 4          // U_/256 partial-logit slabs

typedef _Float16 f16x8 __attribute__((ext_vector_type(8)));
typedef _Float16 f16x4 __attribute__((ext_vector_type(4)));
typedef float f32x4 __attribute__((ext_vector_type(4)));
typedef float f32x16 __attribute__((ext_vector_type(16)));

__device__ __forceinline__ float fast_tanh(float x) {
    float xc = fminf(fmaxf(x, -10.f), 10.f);
    float e = __expf(2.f * xc);
    return 1.f - 2.f / (e + 1.f);
}

__device__ __forceinline__ void load_lds16(const void* g, void* l) {
    __builtin_amdgcn_global_load_lds(
        (const __attribute__((address_space(1))) void*)g,
        (__attribute__((address_space(3))) void*)l, 16, 0, 0);
}

// ---------------- features f32 -> f16 (linear copy) ----------------
__global__ void precast_kernel(const float* __restrict__ in,
                               _Float16* __restrict__ out) {
    size_t i = (size_t)blockIdx.x * 256 + threadIdx.x;
    const size_t stride = (size_t)2048 * 256;
    const size_t n8 = (size_t)M_ * D_ / 8;
    for (size_t j = i; j < n8; j += stride) {
        f32x4 a = *(const f32x4*)(in + j * 8);
        f32x4 b = *(const f32x4*)(in + j * 8 + 4);
        f16x8 h;
        h[0] = (_Float16)a[0]; h[1] = (_Float16)a[1];
        h[2] = (_Float16)a[2]; h[3] = (_Float16)a[3];
        h[4] = (_Float16)b[0]; h[5] = (_Float16)b[1];
        h[6] = (_Float16)b[2]; h[7] = (_Float16)b[3];
        *(f16x8*)(out + j * 8) = h;
    }
}

// ---------------- W1 [D][U] f32 -> W1t [U][D] f16 ----------------
__global__ void transpose_cast_kernel(const float* __restrict__ W1,
                                      _Float16* __restrict__ W1t) {
    int u = blockIdx.x * 256 + threadIdx.x;   // grid.x = 4
    int d0 = blockIdx.y * 64;                 // grid.y = 16
    for (int j8 = 0; j8 < 8; ++j8) {
        f16x8 h;
        #pragma unroll
        for (int j = 0; j < 8; ++j)
            h[j] = (_Float16)W1[(size_t)(d0 + j8 * 8 + j) * U_ + u];
        *(f16x8*)&W1t[(size_t)u * D_ + d0 + j8 * 8] = h;
    }
}

// ---------------- proj_h ----------------
__global__ void proj_h_partial_kernel(const float* __restrict__ hidden,
                                      const float* __restrict__ W2,
                                      float* __restrict__ pph) {
    int u = blockIdx.x * 256 + threadIdx.x;   // grid.x = 4
    int c = blockIdx.y;                       // grid.y = 8
    __shared__ float hb[32][128];
    for (int i = threadIdx.x; i < 32 * 128; i += 256)
        hb[i >> 7][i & 127] = hidden[(i >> 7) * D_ + c * 128 + (i & 127)];
    __syncthreads();
    float acc[32] = {};
    for (int d = 0; d < 128; ++d) {
        float w = W2[(size_t)(c * 128 + d) * U_ + u];
        #pragma unroll
        for (int b = 0; b < 32; ++b) acc[b] = fmaf(hb[b][d], w, acc[b]);
    }
    #pragma unroll
    for (int b = 0; b < 32; ++b)
        pph[((size_t)c * 32 + b) * U_ + u] = acc[b];
}

__global__ void proj_h_combine_kernel(const float* __restrict__ pph,
                                      const float* __restrict__ b1,
                                      const float* __restrict__ b2,
                                      float* __restrict__ ph) {
    int u = blockIdx.x * 256 + threadIdx.x;
    float bias = b1[u] + b2[u];
    for (int b = 0; b < 32; ++b) {
        float s = bias;
        #pragma unroll
        for (int c = 0; c < 8; ++c) s += pph[((size_t)c * 32 + b) * U_ + u];
        ph[b * U_ + u] = s;
    }
}

// ============ fused 256x256 GEMM (32x32x16 MFMA) + tanh + dot(V) ============
// 512 thr = 8 waves (2M x 4N), wave tile 128x64 = 4 mtiles(32) x 2 ntiles(32).
// LDS 128KB: per buf b: A [kh][256 rows][64B] @ b*64K, B same @ +32K.
// 2-bit XOR swizzle: phys 16B-unit = logical ^ ((row>>1)&3), both sides.
// A (featH f16) and B (W1t f16) staged via global_load_lds, linear dest +
// inverse-swizzled per-lane global source.
// 4 phases/K-tile: (kh0,mh0)(kh0,mh1)(kh1,mh0)(kh1,mh1); stage stagger
// A-kh0 / B-kh0+VM4 / A-kh1 / B-kh1+VM4 (r3-proven counted-vmcnt discipline).

#define SB0 __builtin_amdgcn_sched_barrier(0);
#define BAR __builtin_amdgcn_s_barrier();
#define LGKM0 asm volatile("s_waitcnt lgkmcnt(0)" ::: "memory");
#define VM4 asm volatile("s_waitcnt vmcnt(4)" ::: "memory");
#define VM0 asm volatile("s_waitcnt vmcnt(0)" ::: "memory");

#define STAGE_A(bb, kh, kof) do { \
    load_lds16(Ag + sA0 + (kof) + (kh) * 64, \
               smem + (bb) * 65536 + (kh) * 16384 + tid * 16); \
    load_lds16(Ag + sA1 + (kof) + (kh) * 64, \
               smem + (bb) * 65536 + (kh) * 16384 + 8192 + tid * 16); \
} while (0)

#define STAGE_B(bb, kh, kof) do { \
    load_lds16(Bg + sA0 + (kof) + (kh) * 64, \
               smem + (bb) * 65536 + 32768 + (kh) * 16384 + tid * 16); \
    load_lds16(Bg + sA1 + (kof) + (kh) * 64, \
               smem + (bb) * 65536 + 32768 + (kh) * 16384 + 8192 + tid * 16); \
} while (0)

// af[mt][ks], bf[nt][ks]: 8 f16 at row=(l&31)-based, k=ks*16+(l>>5)*8+j
#define READ_AF(bb, kh, mh) do { \
    const char* ab_ = smem + (bb) * 65536 + (kh) * 16384; \
    _Pragma("unroll") \
    for (int mt_ = 0; mt_ < 2; ++mt_) { \
        int r_ = (wr * 128 + ((mh) * 2 + mt_) * 32 + l31) * 64; \
        _Pragma("unroll") \
        for (int ks_ = 0; ks_ < 2; ++ks_) \
            af[mt_][ks_] = *(const f16x8*)(ab_ + r_ + (((ks_ * 2 + hi) ^ rsw) << 4)); \
    } \
} while (0)

#define READ_BF(bb, kh) do { \
    const char* bp_ = smem + (bb) * 65536 + 32768 + (kh) * 16384; \
    _Pragma("unroll") \
    for (int nt_ = 0; nt_ < 2; ++nt_) { \
        int r_ = (wc * 64 + nt_ * 32 + l31) * 64; \
        _Pragma("unroll") \
        for (int ks_ = 0; ks_ < 2; ++ks_) \
            bf[nt_][ks_] = *(const f16x8*)(bp_ + r_ + (((ks_ * 2 + hi) ^ rsw) << 4)); \
    } \
} while (0)

#define MFMA8(mh) do { \
    _Pragma("unroll") \
    for (int ks_ = 0; ks_ < 2; ++ks_) \
        _Pragma("unroll") \
        for (int mt_ = 0; mt_ < 2; ++mt_) \
            _Pragma("unroll") \
            for (int nt_ = 0; nt_ < 2; ++nt_) \
                acc[(mh) * 2 + mt_][nt_] = __builtin_amdgcn_mfma_f32_32x32x16_f16( \
                    af[mt_][ks_], bf[nt_][ks_], acc[(mh) * 2 + mt_][nt_], 0, 0, 0); \
} while (0)

#define PH_SYNC(MH) do { \
    SB0 BAR LGKM0 SB0 \
    __builtin_amdgcn_s_setprio(1); \
    MFMA8(MH); \
    __builtin_amdgcn_s_setprio(0); \
    SB0 BAR SB0 \
} while (0)

__global__ __launch_bounds__(512, 2)
void gemm_logits_v6_kernel(const _Float16* __restrict__ A,   // featH [M][D]
                           const _Float16* __restrict__ Bt,  // W1t [U][D]
                           const float* __restrict__ ph,
                           const float* __restrict__ V,
                           float* __restrict__ part)         // [NT_][M]
{
    __shared__ __align__(16) char smem[131072];

    // XCD-chunked mapping: 1024 blocks; xcd owns contiguous 32 mt x 4 nt.
    int bid = blockIdx.x;
    int xcd = bid & 7, local = bid >> 3;
    int mt = xcd * 32 + (local >> 2);   // 0..255
    int nt = local & 3;                 // 0..3

    int tid = threadIdx.x;
    int l = tid & 63, wid = tid >> 6;
    int wr = wid >> 2, wc = wid & 3;    // 2M x 4N waves
    int l31 = l & 31, hi = l >> 5;
    int rsw = (l31 >> 1) & 3;           // read-side 2-bit swizzle

    const char* Ag = (const char*)(A + (size_t)mt * 256 * D_);
    const char* Bg = (const char*)(Bt + (size_t)nt * 256 * D_);

    // staging: thread covers rows (tid>>2) and (tid>>2)+128, one 16B unit each
    int srow = tid >> 2;
    int sunit = ((tid & 3) ^ ((srow >> 1) & 3)) * 16;   // inverse-swizzled source
    size_t sA0 = (size_t)srow * 2048 + sunit;
    size_t sA1 = (size_t)(srow + 128) * 2048 + sunit;

    f32x16 acc[4][2] = {};
    f16x8 af[2][2], bf[2][2];

    // ---- prologue: stage tile 0 fully ----
    STAGE_A(0, 0, 0); STAGE_B(0, 0, 0); STAGE_A(0, 1, 0); STAGE_B(0, 1, 0);
    SB0 VM0 SB0 BAR SB0

    #pragma unroll 1
    for (int t = 0; t < 16; ++t) {
        int bb = t & 1, nb = bb ^ 1;
        int kof = (t + 1) * 128;
        bool pf = (t < 15);

        // phase 1: (kh0, mh0)
        READ_BF(bb, 0);
        READ_AF(bb, 0, 0);
        if (pf) STAGE_A(nb, 0, kof);
        PH_SYNC(0);

        // phase 2: (kh0, mh1)
        READ_AF(bb, 0, 1);
        if (pf) { STAGE_B(nb, 0, kof); SB0 VM4 SB0 }
        else    { SB0 VM0 SB0 }
        PH_SYNC(1);

        // phase 3: (kh1, mh0)
        READ_BF(bb, 1);
        READ_AF(bb, 1, 0);
        if (pf) STAGE_A(nb, 1, kof);
        PH_SYNC(0);

        // phase 4: (kh1, mh1)
        READ_AF(bb, 1, 1);
        if (pf) { STAGE_B(nb, 1, kof); SB0 VM4 SB0 }
        PH_SYNC(1);
    }

    // ---- fused epilogue: s = tanh(acc + ph[b][u]); partial = sum_u s*V[u] ----
    // C/D layout (32x32): col = l&31, row = (reg&3) + 8*(reg>>2) + 4*hi
    int bidx = mt >> 3;               // 8 m-tiles of 256 per batch
    const float* phb = ph + bidx * U_;
    float Vv[2], phv[2];
    #pragma unroll
    for (int nt_ = 0; nt_ < 2; ++nt_) {
        int u = nt * 256 + wc * 64 + nt_ * 32 + l31;
        Vv[nt_] = V[u];
        phv[nt_] = phb[u];
    }
    float* lbuf = (float*)smem;   // buf0 region; tile 15 used buf1 -> disjoint
    #pragma unroll
    for (int mt_ = 0; mt_ < 4; ++mt_) {
        #pragma unroll
        for (int reg = 0; reg < 16; ++reg) {
            float s0 = fast_tanh(acc[mt_][0][reg] + phv[0]);
            float s1 = fast_tanh(acc[mt_][1][reg] + phv[1]);
            float p = fmaf(s0, Vv[0], s1 * Vv[1]);
            #pragma unroll
            for (int off = 1; off < 32; off <<= 1)
                p += __shfl_xor(p, off, 64);
            if (l31 == 0) {
                int row = wr * 128 + mt_ * 32 + (reg & 3) + 8 * (reg >> 2) + 4 * hi;
                lbuf[wc * 256 + row] = p;
            }
        }
    }
    __syncthreads();
    if (tid < 256) {
        float v = lbuf[tid] + lbuf[256 + tid] + lbuf[512 + tid] + lbuf[768 + tid];
        part[(size_t)nt * M_ + mt * 256 + tid] = v;
    }
}

// ---------------- softmax over T per batch ----------------
__global__ void softmax_kernel(const float* __restrict__ part,
                               float* __restrict__ wout) {
    int b = blockIdx.x;
    int tid = threadIdx.x;
    __shared__ float red[8];
    float lg[8];
    #pragma unroll
    for (int j = 0; j < 8; ++j) {
        int t = tid + j * 256;
        float s = 0.f;
        #pragma unroll
        for (int p = 0; p < NT_; ++p)
            s += part[(size_t)p * M_ + b * T_ + t];
        lg[j] = s;
    }
    float mx = lg[0];
    #pragma unroll
    for (int j = 1; j < 8; ++j) mx = fmaxf(mx, lg[j]);
    #pragma unroll
    for (int off = 1; off < 64; off <<= 1) mx = fmaxf(mx, __shfl_xor(mx, off, 64));
    int wv = tid >> 6;
    if ((tid & 63) == 0) red[wv] = mx;
    __syncthreads();
    mx = fmaxf(fmaxf(red[0], red[1]), fmaxf(red[2], red[3]));
    float e[8];
    float sum = 0.f;
    #pragma unroll
    for (int j = 0; j < 8; ++j) { e[j] = __expf(lg[j] - mx); sum += e[j]; }
    #pragma unroll
    for (int off = 1; off < 64; off <<= 1) sum += __shfl_xor(sum, off, 64);
    if ((tid & 63) == 0) red[4 + wv] = sum;
    __syncthreads();
    sum = red[4] + red[5] + red[6] + red[7];
    float inv = 1.f / sum;
    #pragma unroll
    for (int j = 0; j < 8; ++j)
        wout[b * T_ + tid + j * 256] = e[j] * inv;
}

// ---------------- context = sum_t w_t * features[b,t,:] (f16 copy) ----------------
#define TCH 128
__global__ void context_partial_f16_kernel(const _Float16* __restrict__ feats,
                                           const float* __restrict__ w,
                                           float* __restrict__ cpart) {
    int b = blockIdx.x, tc = blockIdx.y, tid = threadIdx.x;
    f32x4 acc = {0.f, 0.f, 0.f, 0.f};
    const _Float16* f = feats + ((size_t)b * T_ + tc * TCH) * D_ + tid * 4;
    const float* wp = w + b * T_ + tc * TCH;
    #pragma unroll 4
    for (int t = 0; t < TCH; ++t) {
        float wt = wp[t];
        f16x4 fv = *(const f16x4*)(f + (size_t)t * D_);
        acc[0] = fmaf(wt, (float)fv[0], acc[0]);
        acc[1] = fmaf(wt, (float)fv[1], acc[1]);
        acc[2] = fmaf(wt, (float)fv[2], acc[2]);
        acc[3] = fmaf(wt, (float)fv[3], acc[3]);
    }
    *(f32x4*)&cpart[((size_t)tc * B_ + b) * D_ + tid * 4] = acc;
}

__global__ void context_reduce_kernel(const float* __restrict__ cpart,
                                      float* __restrict__ out) {
    int i = blockIdx.x * 256 + threadIdx.x;
    float s = 0.f;
    #pragma unroll
    for (int tc = 0; tc < 16; ++tc)
        s += cpart[(size_t)tc * (B_ * D_) + i];
    out[i] = s;
}

extern "C" void kernel_launch(void* const* d_in, const int* in_sizes, int n_in,
                              void* d_out, int out_size, void* d_ws, size_t ws_size,
                              hipStream_t stream) {
    const float* features = (const float*)d_in[0];
    const float* hidden   = (const float*)d_in[1];
    const float* W1       = (const float*)d_in[2];
    const float* b1       = (const float*)d_in[3];
    const float* W2       = (const float*)d_in[4];
    const float* b2       = (const float*)d_in[5];
    const float* V        = (const float*)d_in[6];
    // bV drops out of softmax (shift-invariant).

    float* ctx_out = (float*)d_out;            // [B,D]
    float* w_out   = ctx_out + B_ * D_;        // [B,T,1]

    char* ws = (char*)d_ws;
    _Float16* W1t  = (_Float16*)ws;                      // 2 MB @ 0
    float* ph      = (float*)(ws + (size_t)(2 << 20));   // 128 KB @ 2M
    float* pph     = (float*)(ws + (size_t)(3 << 20));   // 1 MB @ 3M
    float* part    = (float*)(ws + (size_t)(4 << 20));   // 1 MB @ 4M
    float* cpart   = (float*)(ws + (size_t)(6 << 20));   // 2 MB @ 6M
    _Float16* featH = (_Float16*)(ws + (size_t)(8 << 20)); // 128 MB @ 8M

    transpose_cast_kernel<<<dim3(4, 16), 256, 0, stream>>>(W1, W1t);
    proj_h_partial_kernel<<<dim3(4, 8), 256, 0, stream>>>(hidden, W2, pph);
    proj_h_combine_kernel<<<4, 256, 0, stream>>>(pph, b1, b2, ph);
    precast_kernel<<<2048, 256, 0, stream>>>(features, featH);

    gemm_logits_v6_kernel<<<(M_ / 256) * (U_ / 256), 512, 0, stream>>>(
        featH, W1t, ph, V, part);

    softmax_kernel<<<B_, 256, 0, stream>>>(part, w_out);
    context_partial_f16_kernel<<<dim3(B_, 16), 256, 0, stream>>>(featH, w_out, cpart);
    context_reduce_kernel<<<(B_ * D_) / 256, 256, 0, stream>>>(cpart, ctx_out);
}

// Round 7
// 324.509 us; speedup vs baseline: 1.0980x; 1.0980x over previous
//
#include <hip/hip_runtime.h>
#include <hip/hip_bf16.h>
#include <hip/hip_fp16.h>

#define B_ 32
#define T_ 2048
#define D_ 1024
#define U_ 1024
#define M_ (B_ * T_)   // 65536
#define NT_ 16         // U_/64 col slabs

typedef _Float16 f16x8 __attribute__((ext_vector_type(8)));
typedef float f32x4 __attribute__((ext_vector_type(4)));

__device__ __forceinline__ float fast_tanh(float x) {
    float xc = fminf(fmaxf(x, -10.f), 10.f);
    float e = __expf(2.f * xc);
    return 1.f - 2.f / (e + 1.f);
}

__device__ __forceinline__ void load_lds16(const void* g, void* l) {
    __builtin_amdgcn_global_load_lds(
        (const __attribute__((address_space(1))) void*)g,
        (__attribute__((address_space(3))) void*)l, 16, 0, 0);
}

// ---- precastT: features [M][D] f32 -> featT [M/16][D/8][16 slot][8] f16 ----
// Fragment-order tiles: one MFMA A-frag = 16B at tile + kstep*1024 + lane*16.
__global__ void precastT_kernel(const float* __restrict__ in,
                                _Float16* __restrict__ out) {
    int mt = blockIdx.x;              // 4096 tiles of 16 rows
    int t = threadIdx.x;              // 256
    int slot = t & 15, kb0 = t >> 4;  // kb0 0..15
    const float* src = in + ((size_t)mt * 16 + slot) * D_;
    _Float16* dst = out + (size_t)mt * 16384 + slot * 8;
    #pragma unroll
    for (int i = 0; i < 8; ++i) {
        int kb = kb0 + i * 16;        // 0..127
        f32x4 a = *(const f32x4*)(src + kb * 8);
        f32x4 b = *(const f32x4*)(src + kb * 8 + 4);
        f16x8 h;
        h[0] = (_Float16)a[0]; h[1] = (_Float16)a[1];
        h[2] = (_Float16)a[2]; h[3] = (_Float16)a[3];
        h[4] = (_Float16)b[0]; h[5] = (_Float16)b[1];
        h[6] = (_Float16)b[2]; h[7] = (_Float16)b[3];
        *(f16x8*)(dst + kb * 128) = h;
    }
}

// ---- W1 [D][U] f32 -> W1T tiled [U/16][D/8][16 slot][8] f16 ----
__global__ void transpose_cast_W1T_kernel(const float* __restrict__ W1,
                                          _Float16* __restrict__ W1T) {
    int u = blockIdx.x * 256 + threadIdx.x;   // grid.x = 4
    int d0 = blockIdx.y * 64;                 // grid.y = 16
    _Float16* dst = W1T + (size_t)(u >> 4) * 16384 + (u & 15) * 8;
    for (int j8 = 0; j8 < 8; ++j8) {
        f16x8 h;
        #pragma unroll
        for (int j = 0; j < 8; ++j)
            h[j] = (_Float16)W1[(size_t)(d0 + j8 * 8 + j) * U_ + u];
        *(f16x8*)(dst + (size_t)(d0 / 8 + j8) * 128) = h;
    }
}

// ---------------- proj_h ----------------
__global__ void proj_h_partial_kernel(const float* __restrict__ hidden,
                                      const float* __restrict__ W2,
                                      float* __restrict__ pph) {
    int u = blockIdx.x * 256 + threadIdx.x;   // grid.x = 4
    int c = blockIdx.y;                       // grid.y = 8
    __shared__ float hb[32][128];
    for (int i = threadIdx.x; i < 32 * 128; i += 256)
        hb[i >> 7][i & 127] = hidden[(i >> 7) * D_ + c * 128 + (i & 127)];
    __syncthreads();
    float acc[32] = {};
    for (int d = 0; d < 128; ++d) {
        float w = W2[(size_t)(c * 128 + d) * U_ + u];
        #pragma unroll
        for (int b = 0; b < 32; ++b) acc[b] = fmaf(hb[b][d], w, acc[b]);
    }
    #pragma unroll
    for (int b = 0; b < 32; ++b)
        pph[((size_t)c * 32 + b) * U_ + u] = acc[b];
}

__global__ void proj_h_combine_kernel(const float* __restrict__ pph,
                                      const float* __restrict__ b1,
                                      const float* __restrict__ b2,
                                      float* __restrict__ ph) {
    int u = blockIdx.x * 256 + threadIdx.x;
    float bias = b1[u] + b2[u];
    for (int b = 0; b < 32; ++b) {
        float s = bias;
        #pragma unroll
        for (int c = 0; c < 8; ++c) s += pph[((size_t)c * 32 + b) * U_ + u];
        ph[b * U_ + u] = s;
    }
}

// ============ v7: barrier-free GEMM + tanh + dot(V) ============
// Grid 256 persistent (1 block/CU), 512 thr = 8 waves.
// Block owns 64 u-cols (nt) x 4096 rows (mtcg), processed as 4 chunks of 1024.
// B: W1T slab (4 u-tiles = 128KB) LDS-resident, loaded once, frag-order
//    (reads contiguous per instr -> conflict-free, no swizzle).
// A: featT frag-order tiles streamed HBM/L2 -> regs, dbuf 1 K-step deep.
// Wave owns 128 rows/chunk; NO barriers in the K-loop.

#define LOAD_AF(dst, mtb, s) do { \
    const char* a_ = fT + ((size_t)(mtb) << 15) + (s) * 1024 + l16; \
    _Pragma("unroll") \
    for (int m_ = 0; m_ < 8; ++m_) \
        dst[m_] = *(const f16x8*)(a_ + (m_ << 15)); \
} while (0)

#define READ_BF(s) do { \
    _Pragma("unroll") \
    for (int n_ = 0; n_ < 4; ++n_) \
        bfc[n_] = *(const f16x8*)(lB + n_ * 32768 + (s) * 1024 + l16); \
} while (0)

#define MFMA_STEP(AF) do { \
    __builtin_amdgcn_s_setprio(1); \
    _Pragma("unroll") \
    for (int m_ = 0; m_ < 8; ++m_) \
        _Pragma("unroll") \
        for (int n_ = 0; n_ < 4; ++n_) \
            acc[m_][n_] = __builtin_amdgcn_mfma_f32_16x16x32_f16( \
                AF[m_], bfc[n_], acc[m_][n_], 0, 0, 0); \
    __builtin_amdgcn_s_setprio(0); \
} while (0)

__global__ __launch_bounds__(512, 2)
void gemm_logits_v7_kernel(const _Float16* __restrict__ featT,
                           const _Float16* __restrict__ W1T,
                           const float* __restrict__ ph,
                           const float* __restrict__ V,
                           float* __restrict__ part)   // [NT_][M]
{
    __shared__ __align__(16) _Float16 Bs[65536];   // 128 KB

    int bid = blockIdx.x;                   // 256
    int xcd = bid & 7, local = bid >> 3;    // local 0..31
    int mtcg = xcd * 2 + (local >> 4);      // 0..15 (4096-row group)
    int nt = local & 15;                    // 0..15 (64-col slab)

    int tid = threadIdx.x;
    int l = tid & 63, w = tid >> 6;
    int l16 = l * 16;
    const char* fT = (const char*)featT;
    const char* lB = (const char*)Bs;

    // ---- B prologue: stage 128KB W1T slab, linear ----
    {
        const char* src = (const char*)W1T + (size_t)nt * 131072;
        #pragma unroll
        for (int i = 0; i < 16; ++i)
            load_lds16(src + i * 8192 + tid * 16, (char*)Bs + i * 8192 + tid * 16);
    }

    f16x8 afA[8], afB[8], bfc[4];
    f32x4 acc[8][4] = {};

    // preload chunk0 step0 A-frags (independent of LDS)
    LOAD_AF(afA, mtcg * 256 + w * 8, 0);

    float Vv[4];
    #pragma unroll
    for (int n = 0; n < 4; ++n) Vv[n] = V[nt * 64 + n * 16 + (l & 15)];

    asm volatile("s_waitcnt vmcnt(0)" ::: "memory");
    __builtin_amdgcn_s_barrier();   // the only block-wide barrier

    #pragma unroll 1
    for (int c = 0; c < 4; ++c) {
        int mtb = mtcg * 256 + c * 64 + w * 8;
        int mtbn = (c < 3) ? (mtb + 64) : mtb;   // next chunk (clamped)

        #pragma unroll 1
        for (int s = 0; s < 32; s += 2) {
            READ_BF(s);
            LOAD_AF(afB, mtb, s + 1);
            MFMA_STEP(afA);
            READ_BF(s + 1);
            if (s < 30) LOAD_AF(afA, mtb, s + 2);
            else        LOAD_AF(afA, mtbn, 0);   // prefetch next chunk step0
            MFMA_STEP(afB);
        }

        // ---- epilogue (wave-local rows): s=tanh(acc+ph), partial=sum_u s*V ----
        int row0 = mtcg * 4096 + c * 1024 + w * 128;
        const float* phb = ph + (row0 >> 11) * U_;
        float phv[4];
        #pragma unroll
        for (int n = 0; n < 4; ++n) phv[n] = phb[nt * 64 + n * 16 + (l & 15)];
        #pragma unroll
        for (int m = 0; m < 8; ++m) {
            #pragma unroll
            for (int r = 0; r < 4; ++r) {
                float p = 0.f;
                #pragma unroll
                for (int n = 0; n < 4; ++n)
                    p = fmaf(fast_tanh(acc[m][n][r] + phv[n]), Vv[n], p);
                p += __shfl_xor(p, 1, 64);
                p += __shfl_xor(p, 2, 64);
                p += __shfl_xor(p, 4, 64);
                p += __shfl_xor(p, 8, 64);
                if ((l & 15) == 0)
                    part[(size_t)nt * M_ + row0 + m * 16 + (l >> 4) * 4 + r] = p;
            }
        }
        #pragma unroll
        for (int m = 0; m < 8; ++m)
            #pragma unroll
            for (int n = 0; n < 4; ++n)
                acc[m][n] = (f32x4){0.f, 0.f, 0.f, 0.f};
    }
}

// ---------------- softmax over T per batch ----------------
__global__ void softmax_kernel(const float* __restrict__ part,
                               float* __restrict__ wout) {
    int b = blockIdx.x;
    int tid = threadIdx.x;
    __shared__ float red[8];
    float lg[8];
    #pragma unroll
    for (int j = 0; j < 8; ++j) {
        int t = tid + j * 256;
        float s = 0.f;
        #pragma unroll
        for (int p = 0; p < NT_; ++p)
            s += part[(size_t)p * M_ + b * T_ + t];
        lg[j] = s;
    }
    float mx = lg[0];
    #pragma unroll
    for (int j = 1; j < 8; ++j) mx = fmaxf(mx, lg[j]);
    #pragma unroll
    for (int off = 1; off < 64; off <<= 1) mx = fmaxf(mx, __shfl_xor(mx, off, 64));
    int wv = tid >> 6;
    if ((tid & 63) == 0) red[wv] = mx;
    __syncthreads();
    mx = fmaxf(fmaxf(red[0], red[1]), fmaxf(red[2], red[3]));
    float e[8];
    float sum = 0.f;
    #pragma unroll
    for (int j = 0; j < 8; ++j) { e[j] = __expf(lg[j] - mx); sum += e[j]; }
    #pragma unroll
    for (int off = 1; off < 64; off <<= 1) sum += __shfl_xor(sum, off, 64);
    if ((tid & 63) == 0) red[4 + wv] = sum;
    __syncthreads();
    sum = red[4] + red[5] + red[6] + red[7];
    float inv = 1.f / sum;
    #pragma unroll
    for (int j = 0; j < 8; ++j)
        wout[b * T_ + tid + j * 256] = e[j] * inv;
}

// ---- context from featT (tiled): grid (32 b, 8 dchunk), block sole owner ----
__global__ void context_v7_kernel(const _Float16* __restrict__ featT,
                                  const float* __restrict__ w,
                                  float* __restrict__ ctx) {
    int b = blockIdx.x;        // 32
    int dc = blockIdx.y;       // 8 (128 d each)
    int t = threadIdx.x;       // 256
    __shared__ float wLds[2048];
    for (int i = t; i < 2048; i += 256) wLds[i] = w[b * T_ + i];
    __syncthreads();

    float acc[8] = {};
    const char* base = (const char*)featT + (size_t)b * 128 * 32768 + dc * 4096 + t * 16;
    int slot = t & 15;
    #pragma unroll 4
    for (int mt = 0; mt < 128; ++mt) {
        f16x8 v = *(const f16x8*)(base + (size_t)mt * 32768);
        float wt = wLds[mt * 16 + slot];
        #pragma unroll
        for (int j = 0; j < 8; ++j) acc[j] = fmaf(wt, (float)v[j], acc[j]);
    }
    #pragma unroll
    for (int j = 0; j < 8; ++j) {
        acc[j] += __shfl_xor(acc[j], 1, 64);
        acc[j] += __shfl_xor(acc[j], 2, 64);
        acc[j] += __shfl_xor(acc[j], 4, 64);
        acc[j] += __shfl_xor(acc[j], 8, 64);
    }
    if ((t & 15) == 0) {
        float* o = ctx + b * D_ + dc * 128 + (t >> 4) * 8;
        #pragma unroll
        for (int j = 0; j < 8; ++j) o[j] = acc[j];
    }
}

extern "C" void kernel_launch(void* const* d_in, const int* in_sizes, int n_in,
                              void* d_out, int out_size, void* d_ws, size_t ws_size,
                              hipStream_t stream) {
    const float* features = (const float*)d_in[0];
    const float* hidden   = (const float*)d_in[1];
    const float* W1       = (const float*)d_in[2];
    const float* b1       = (const float*)d_in[3];
    const float* W2       = (const float*)d_in[4];
    const float* b2       = (const float*)d_in[5];
    const float* V        = (const float*)d_in[6];
    // bV drops out of softmax (shift-invariant).

    float* ctx_out = (float*)d_out;            // [B,D]
    float* w_out   = ctx_out + B_ * D_;        // [B,T,1]

    char* ws = (char*)d_ws;
    _Float16* W1T  = (_Float16*)ws;                               // 2 MB @ 0
    float* ph      = (float*)(ws + (size_t)(2 << 20));            // 128 KB @ 2M
    float* pph     = (float*)(ws + (size_t)(2 << 20) + (1 << 17)); // 1 MB
    float* part    = (float*)(ws + (size_t)(4 << 20));            // 4 MB @ 4M
    _Float16* featT = (_Float16*)(ws + (size_t)(8 << 20));        // 128 MB @ 8M

    transpose_cast_W1T_kernel<<<dim3(4, 16), 256, 0, stream>>>(W1, W1T);
    proj_h_partial_kernel<<<dim3(4, 8), 256, 0, stream>>>(hidden, W2, pph);
    proj_h_combine_kernel<<<4, 256, 0, stream>>>(pph, b1, b2, ph);
    precastT_kernel<<<4096, 256, 0, stream>>>(features, featT);

    gemm_logits_v7_kernel<<<256, 512, 0, stream>>>(featT, W1T, ph, V, part);

    softmax_kernel<<<B_, 256, 0, stream>>>(part, w_out);
    context_v7_kernel<<<dim3(B_, 8), 256, 0, stream>>>(featT, w_out, ctx_out);
}

// Round 9
// 314.837 us; speedup vs baseline: 1.1317x; 1.0307x over previous
//
#include <hip/hip_runtime.h>
#include <hip/hip_bf16.h>
#include <hip/hip_fp16.h>

#define B_ 32
#define T_ 2048
#define D_ 1024
#define U_ 1024
#define M_ (B_ * T_)   // 65536
#define NT_ 16         // U_/64 col slabs

typedef _Float16 f16x8 __attribute__((ext_vector_type(8)));
typedef float f32x4 __attribute__((ext_vector_type(4)));

__device__ __forceinline__ float fast_tanh(float x) {
    float xc = fminf(fmaxf(x, -10.f), 10.f);
    float e = __expf(2.f * xc);
    return 1.f - 2.f / (e + 1.f);
}

__device__ __forceinline__ void load_lds16(const void* g, void* l) {
    __builtin_amdgcn_global_load_lds(
        (const __attribute__((address_space(1))) void*)g,
        (__attribute__((address_space(3))) void*)l, 16, 0, 0);
}

// ---- precastT: features [M][D] f32 -> featT [M/16][D/8][16 slot][8] f16 ----
// Coalesced reads (64B/lane row-major) -> XOR-swizzled LDS -> coalesced
// frag-order writes (wave writes 1KB contiguous).
__global__ void precastT_kernel(const float* __restrict__ in,
                                _Float16* __restrict__ out) {
    __shared__ __align__(16) _Float16 lds[16 * 1024];   // 32 KB, [row][128 units]
    int mt = blockIdx.x;              // 4096 tiles of 16 rows
    int t = threadIdx.x;              // 256
    const float* src = in + (size_t)mt * 16384;
    #pragma unroll
    for (int i = 0; i < 4; ++i) {
        int o = (i * 256 + t) * 16;           // flat f32 offset
        int r = o >> 10, c = o & 1023;
        f32x4 a0 = *(const f32x4*)(src + o);
        f32x4 a1 = *(const f32x4*)(src + o + 4);
        f32x4 a2 = *(const f32x4*)(src + o + 8);
        f32x4 a3 = *(const f32x4*)(src + o + 12);
        f16x8 h0, h1;
        h0[0]=(_Float16)a0[0]; h0[1]=(_Float16)a0[1]; h0[2]=(_Float16)a0[2]; h0[3]=(_Float16)a0[3];
        h0[4]=(_Float16)a1[0]; h0[5]=(_Float16)a1[1]; h0[6]=(_Float16)a1[2]; h0[7]=(_Float16)a1[3];
        h1[0]=(_Float16)a2[0]; h1[1]=(_Float16)a2[1]; h1[2]=(_Float16)a2[2]; h1[3]=(_Float16)a2[3];
        h1[4]=(_Float16)a3[0]; h1[5]=(_Float16)a3[1]; h1[6]=(_Float16)a3[2]; h1[7]=(_Float16)a3[3];
        int u0 = c >> 3, swz = r & 7;
        *(f16x8*)((char*)lds + r * 2048 + ((u0 ^ swz) << 4)) = h0;
        *(f16x8*)((char*)lds + r * 2048 + (((u0 + 1) ^ swz) << 4)) = h1;
    }
    __syncthreads();
    int slot = t & 15, kb0 = t >> 4, ssw = slot & 7;
    _Float16* dst = out + (size_t)mt * 16384 + slot * 8;
    #pragma unroll
    for (int i = 0; i < 8; ++i) {
        int kb = kb0 + i * 16;
        f16x8 h = *(const f16x8*)((char*)lds + slot * 2048 + ((kb ^ ssw) << 4));
        *(f16x8*)(dst + kb * 128) = h;
    }
}

// ---- W1 [D][U] f32 -> W1T tiled [U/16][D/8][16 slot][8] f16 ----
__global__ void transpose_cast_W1T_kernel(const float* __restrict__ W1,
                                          _Float16* __restrict__ W1T) {
    int u = blockIdx.x * 256 + threadIdx.x;   // grid.x = 4
    int d0 = blockIdx.y * 64;                 // grid.y = 16
    _Float16* dst = W1T + (size_t)(u >> 4) * 16384 + (u & 15) * 8;
    for (int j8 = 0; j8 < 8; ++j8) {
        f16x8 h;
        #pragma unroll
        for (int j = 0; j < 8; ++j)
            h[j] = (_Float16)W1[(size_t)(d0 + j8 * 8 + j) * U_ + u];
        *(f16x8*)(dst + (size_t)(d0 / 8 + j8) * 128) = h;
    }
}

// ---------------- proj_h ----------------
__global__ void proj_h_partial_kernel(const float* __restrict__ hidden,
                                      const float* __restrict__ W2,
                                      float* __restrict__ pph) {
    int u = blockIdx.x * 256 + threadIdx.x;   // grid.x = 4
    int c = blockIdx.y;                       // grid.y = 8
    __shared__ float hb[32][128];
    for (int i = threadIdx.x; i < 32 * 128; i += 256)
        hb[i >> 7][i & 127] = hidden[(i >> 7) * D_ + c * 128 + (i & 127)];
    __syncthreads();
    float acc[32] = {};
    for (int d = 0; d < 128; ++d) {
        float w = W2[(size_t)(c * 128 + d) * U_ + u];
        #pragma unroll
        for (int b = 0; b < 32; ++b) acc[b] = fmaf(hb[b][d], w, acc[b]);
    }
    #pragma unroll
    for (int b = 0; b < 32; ++b)
        pph[((size_t)c * 32 + b) * U_ + u] = acc[b];
}

__global__ void proj_h_combine_kernel(const float* __restrict__ pph,
                                      const float* __restrict__ b1,
                                      const float* __restrict__ b2,
                                      float* __restrict__ ph) {
    int u = blockIdx.x * 256 + threadIdx.x;
    float bias = b1[u] + b2[u];
    for (int b = 0; b < 32; ++b) {
        float s = bias;
        #pragma unroll
        for (int c = 0; c < 8; ++c) s += pph[((size_t)c * 32 + b) * U_ + u];
        ph[b * U_ + u] = s;
    }
}

// ============ v8b: barrier-free GEMM, 16 waves/block (mapping fixed) ============
// Grid 1024 blocks (1 res/CU), 1024 thr = 16 waves -> 4 waves/SIMD.
// Block owns 64 u-cols (nt) x 1024 rows (mg: 0..63 = xcd*8 + local>>4).
// B: W1T slab (4 u-tiles = 128KB) LDS-resident, loaded once, frag-order.
// A: featT frag-order streamed HBM/L2 -> regs, dbuf 1 K-step. No K-loop barriers.

#define LOAD_AF(dst, s) do { \
    const char* a_ = aT + (s) * 1024; \
    _Pragma("unroll") \
    for (int m_ = 0; m_ < 4; ++m_) \
        dst[m_] = *(const f16x8*)(a_ + (m_ << 15)); \
} while (0)

#define READ_BF(s) do { \
    _Pragma("unroll") \
    for (int n_ = 0; n_ < 4; ++n_) \
        bfc[n_] = *(const f16x8*)(lB + n_ * 32768 + (s) * 1024 + l16); \
} while (0)

#define MFMA_STEP(AF) do { \
    __builtin_amdgcn_s_setprio(1); \
    _Pragma("unroll") \
    for (int m_ = 0; m_ < 4; ++m_) \
        _Pragma("unroll") \
        for (int n_ = 0; n_ < 4; ++n_) \
            acc[m_][n_] = __builtin_amdgcn_mfma_f32_16x16x32_f16( \
                AF[m_], bfc[n_], acc[m_][n_], 0, 0, 0); \
    __builtin_amdgcn_s_setprio(0); \
} while (0)

__global__ __launch_bounds__(1024, 4)
void gemm_logits_v8_kernel(const _Float16* __restrict__ featT,
                           const _Float16* __restrict__ W1T,
                           const float* __restrict__ ph,
                           const float* __restrict__ V,
                           float* __restrict__ part)   // [NT_][M]
{
    __shared__ __align__(16) _Float16 Bs[65536];   // 128 KB

    int bid = blockIdx.x;                   // 1024
    int xcd = bid & 7, local = bid >> 3;    // local 0..127
    int nt = local & 15;                    // 0..15 (64-col slab)
    int mg = xcd * 8 + (local >> 4);        // 0..63 (1024-row group) — FIXED

    int tid = threadIdx.x;
    int l = tid & 63, w = tid >> 6;         // 16 waves
    int l16 = l * 16;
    const char* lB = (const char*)Bs;

    // wave's 4 A-tiles (16 rows each): tile0 = mg*64 + w*4
    const char* aT = (const char*)featT + ((size_t)(mg * 64 + w * 4) << 15) + l16;

    // ---- B prologue: stage 128KB W1T slab, linear ----
    {
        const char* src = (const char*)W1T + (size_t)nt * 131072;
        #pragma unroll
        for (int i = 0; i < 8; ++i)
            load_lds16(src + i * 16384 + tid * 16, (char*)Bs + i * 16384 + tid * 16);
    }

    f16x8 afA[4], afB[4], bfc[4];
    f32x4 acc[4][4] = {};

    LOAD_AF(afA, 0);   // step0 A-frags (register loads, independent of LDS)

    float Vv[4];
    #pragma unroll
    for (int n = 0; n < 4; ++n) Vv[n] = V[nt * 64 + n * 16 + (l & 15)];

    asm volatile("s_waitcnt vmcnt(0)" ::: "memory");
    __builtin_amdgcn_s_barrier();   // the only block-wide barrier

    #pragma unroll 1
    for (int s = 0; s < 32; s += 2) {
        READ_BF(s);
        LOAD_AF(afB, s + 1);
        MFMA_STEP(afA);
        READ_BF(s + 1);
        if (s < 30) LOAD_AF(afA, s + 2);
        MFMA_STEP(afB);
    }

    // ---- epilogue (wave-local rows): s=tanh(acc+ph), partial=sum_u s*V ----
    int row0 = mg * 1024 + w * 64;
    const float* phb = ph + (mg >> 1) * U_;
    float phv[4];
    #pragma unroll
    for (int n = 0; n < 4; ++n) phv[n] = phb[nt * 64 + n * 16 + (l & 15)];
    #pragma unroll
    for (int m = 0; m < 4; ++m) {
        #pragma unroll
        for (int r = 0; r < 4; ++r) {
            float p = 0.f;
            #pragma unroll
            for (int n = 0; n < 4; ++n)
                p = fmaf(fast_tanh(acc[m][n][r] + phv[n]), Vv[n], p);
            p += __shfl_xor(p, 1, 64);
            p += __shfl_xor(p, 2, 64);
            p += __shfl_xor(p, 4, 64);
            p += __shfl_xor(p, 8, 64);
            if ((l & 15) == 0)
                part[(size_t)nt * M_ + row0 + m * 16 + (l >> 4) * 4 + r] = p;
        }
    }
}

// ---------------- softmax over T per batch ----------------
__global__ void softmax_kernel(const float* __restrict__ part,
                               float* __restrict__ wout) {
    int b = blockIdx.x;
    int tid = threadIdx.x;
    __shared__ float red[8];
    float lg[8];
    #pragma unroll
    for (int j = 0; j < 8; ++j) {
        int t = tid + j * 256;
        float s = 0.f;
        #pragma unroll
        for (int p = 0; p < NT_; ++p)
            s += part[(size_t)p * M_ + b * T_ + t];
        lg[j] = s;
    }
    float mx = lg[0];
    #pragma unroll
    for (int j = 1; j < 8; ++j) mx = fmaxf(mx, lg[j]);
    #pragma unroll
    for (int off = 1; off < 64; off <<= 1) mx = fmaxf(mx, __shfl_xor(mx, off, 64));
    int wv = tid >> 6;
    if ((tid & 63) == 0) red[wv] = mx;
    __syncthreads();
    mx = fmaxf(fmaxf(red[0], red[1]), fmaxf(red[2], red[3]));
    float e[8];
    float sum = 0.f;
    #pragma unroll
    for (int j = 0; j < 8; ++j) { e[j] = __expf(lg[j] - mx); sum += e[j]; }
    #pragma unroll
    for (int off = 1; off < 64; off <<= 1) sum += __shfl_xor(sum, off, 64);
    if ((tid & 63) == 0) red[4 + wv] = sum;
    __syncthreads();
    sum = red[4] + red[5] + red[6] + red[7];
    float inv = 1.f / sum;
    #pragma unroll
    for (int j = 0; j < 8; ++j)
        wout[b * T_ + tid + j * 256] = e[j] * inv;
}

// ---- context from featT (tiled): grid (32 b, 8 dchunk) ----
__global__ void context_v7_kernel(const _Float16* __restrict__ featT,
                                  const float* __restrict__ w,
                                  float* __restrict__ ctx) {
    int b = blockIdx.x;        // 32
    int dc = blockIdx.y;       // 8 (128 d each)
    int t = threadIdx.x;       // 256
    __shared__ float wLds[2048];
    for (int i = t; i < 2048; i += 256) wLds[i] = w[b * T_ + i];
    __syncthreads();

    float acc[8] = {};
    const char* base = (const char*)featT + (size_t)b * 128 * 32768 + dc * 4096 + t * 16;
    int slot = t & 15;
    #pragma unroll 4
    for (int mt = 0; mt < 128; ++mt) {
        f16x8 v = *(const f16x8*)(base + (size_t)mt * 32768);
        float wt = wLds[mt * 16 + slot];
        #pragma unroll
        for (int j = 0; j < 8; ++j) acc[j] = fmaf(wt, (float)v[j], acc[j]);
    }
    #pragma unroll
    for (int j = 0; j < 8; ++j) {
        acc[j] += __shfl_xor(acc[j], 1, 64);
        acc[j] += __shfl_xor(acc[j], 2, 64);
        acc[j] += __shfl_xor(acc[j], 4, 64);
        acc[j] += __shfl_xor(acc[j], 8, 64);
    }
    if ((t & 15) == 0) {
        float* o = ctx + b * D_ + dc * 128 + (t >> 4) * 8;
        #pragma unroll
        for (int j = 0; j < 8; ++j) o[j] = acc[j];
    }
}

extern "C" void kernel_launch(void* const* d_in, const int* in_sizes, int n_in,
                              void* d_out, int out_size, void* d_ws, size_t ws_size,
                              hipStream_t stream) {
    const float* features = (const float*)d_in[0];
    const float* hidden   = (const float*)d_in[1];
    const float* W1       = (const float*)d_in[2];
    const float* b1       = (const float*)d_in[3];
    const float* W2       = (const float*)d_in[4];
    const float* b2       = (const float*)d_in[5];
    const float* V        = (const float*)d_in[6];
    // bV drops out of softmax (shift-invariant).

    float* ctx_out = (float*)d_out;            // [B,D]
    float* w_out   = ctx_out + B_ * D_;        // [B,T,1]

    char* ws = (char*)d_ws;
    _Float16* W1T  = (_Float16*)ws;                               // 2 MB @ 0
    float* ph      = (float*)(ws + (size_t)(2 << 20));            // 128 KB @ 2M
    float* pph     = (float*)(ws + (size_t)(2 << 20) + (1 << 17)); // 1 MB
    float* part    = (float*)(ws + (size_t)(4 << 20));            // 4 MB @ 4M
    _Float16* featT = (_Float16*)(ws + (size_t)(8 << 20));        // 128 MB @ 8M

    transpose_cast_W1T_kernel<<<dim3(4, 16), 256, 0, stream>>>(W1, W1T);
    proj_h_partial_kernel<<<dim3(4, 8), 256, 0, stream>>>(hidden, W2, pph);
    proj_h_combine_kernel<<<4, 256, 0, stream>>>(pph, b1, b2, ph);
    precastT_kernel<<<4096, 256, 0, stream>>>(features, featT);

    gemm_logits_v8_kernel<<<1024, 1024, 0, stream>>>(featT, W1T, ph, V, part);

    softmax_kernel<<<B_, 256, 0, stream>>>(part, w_out);
    context_v7_kernel<<<dim3(B_, 8), 256, 0, stream>>>(featT, w_out, ctx_out);
}